// Round 4
// baseline (88.255 us; speedup 1.0000x reference)
//
#include <hip/hip_runtime.h>

constexpr int   ND_  = 16;
constexpr int   C_   = 512;
constexpr float EPS_ = 1e-5f;
constexpr int   NREP = 8;     // accumulator replicas (cuts atomic contention 256->32)

// ---------------- Kernel 1: stats via replicated global atomics -----------
// grid = (2, NCHUNK); block = 256 = 2 row-groups x 128 channel-lanes(float2).
// Block (bx, by): channels [bx*256, +256) of rows [by*256, +256). Row-group g
// accumulates into its own LDS set (no cross-wave RMW), merged, then dumped
// via unsafeAtomicAdd (hw global_atomic_add_f32) into replica (by & 7).
// Replaces R3's 33.5MB partial write + 33.5MB finalize read with ~0 HBM.
__global__ __launch_bounds__(256) void k_stats(
    const float2* __restrict__ X2, const int* __restrict__ dd,
    float* __restrict__ acc_sum, float* __restrict__ acc_sq,
    int* __restrict__ cnt, int rows_per_chunk, int N) {
  __shared__ float2 ssum[2][ND_][128];
  __shared__ float2 ssq [2][ND_][128];
  __shared__ int    sd[256];        // domain id per row of this chunk
  __shared__ int    scnt[ND_];

  const int tid  = threadIdx.x;
  const int g    = tid >> 7;        // row-group 0/1
  const int lane = tid & 127;       // channel lane (float2)
  const int bx   = blockIdx.x;      // channel half: 0 or 1
  const int by   = blockIdx.y;      // row chunk

  for (int i = tid; i < 2 * ND_ * 128; i += 256) {
    ((float2*)ssum)[i] = make_float2(0.f, 0.f);
    ((float2*)ssq )[i] = make_float2(0.f, 0.f);
  }
  if (tid < ND_) scnt[tid] = 0;
  __syncthreads();

  const int r0 = by * rows_per_chunk;
  const int r1 = min(N, r0 + rows_per_chunk);
  const int nr = r1 - r0;

  for (int i = tid; i < nr; i += 256) {
    const int v = dd[r0 + i];
    sd[i] = v;
    if (bx == 0) atomicAdd(&scnt[v], 1);
  }
  __syncthreads();

  const int jr0 = g * 128;
  const int jr1 = min(nr, jr0 + 128);
  const int ch2 = bx * 128 + lane;  // float2 column index (row = 256 float2)
  #pragma unroll 8
  for (int j = jr0; j < jr1; ++j) {
    const int    dn = sd[j];        // wave-uniform
    const float2 v  = X2[(size_t)(r0 + j) * (C_ / 2) + ch2];
    float2 a = ssum[g][dn][lane];
    a.x += v.x; a.y += v.y;
    ssum[g][dn][lane] = a;
    float2 b = ssq[g][dn][lane];
    b.x = fmaf(v.x, v.x, b.x);
    b.y = fmaf(v.y, v.y, b.y);
    ssq[g][dn][lane] = b;
  }
  __syncthreads();

  // merge row-group 1 into 0
  if (tid < 128) {
    #pragma unroll
    for (int dom = 0; dom < ND_; ++dom) {
      float2 a = ssum[0][dom][tid], a1 = ssum[1][dom][tid];
      a.x += a1.x; a.y += a1.y;
      ssum[0][dom][tid] = a;
      float2 b = ssq[0][dom][tid], b1 = ssq[1][dom][tid];
      b.x += b1.x; b.y += b1.y;
      ssq[0][dom][tid] = b;
    }
  }
  __syncthreads();

  // atomic dump: 16 doms x 256 floats (this channel half) x {sum,sq}
  float* asum = acc_sum + (size_t)(by & (NREP - 1)) * ND_ * C_;
  float* asq  = acc_sq  + (size_t)(by & (NREP - 1)) * ND_ * C_;
  for (int idx = tid; idx < ND_ * 256; idx += 256) {
    const int dom = idx >> 8;       // 256 floats per dom (this half)
    const int ci  = idx & 255;      // channel within half
    const float sv = ((const float*)ssum[0][dom])[ci];
    const float qv = ((const float*)ssq [0][dom])[ci];
    unsafeAtomicAdd(&asum[dom * C_ + bx * 256 + ci], sv);
    unsafeAtomicAdd(&asq [dom * C_ + bx * 256 + ci], qv);
  }
  if (bx == 0 && tid < ND_) atomicAdd(&cnt[tid], scnt[tid]);
}

// ---------------- Kernel 2: replica-sum -> scale/shift --------------------
// 64 blocks x 128 threads = 8192 = 16 domains * 512 channels.
__global__ __launch_bounds__(128) void k_finalize(
    const float* __restrict__ acc_sum, const float* __restrict__ acc_sq,
    const int* __restrict__ cnt, const float* __restrict__ gamma,
    const float* __restrict__ beta, float* __restrict__ scale,
    float* __restrict__ shift) {
  const int gid = blockIdx.x * 128 + threadIdx.x;   // [0, 16*512)
  const int dom = gid >> 9;
  float s = 0.f, q = 0.f;
  #pragma unroll
  for (int r = 0; r < NREP; ++r) {
    s += acc_sum[(size_t)r * ND_ * C_ + gid];
    q += acc_sq [(size_t)r * ND_ * C_ + gid];
  }
  const float fc   = fmaxf((float)cnt[dom], 1.f);
  const float mean = s / fc;
  const float var  = q / fc - mean * mean;
  const float inv  = rsqrtf(var + EPS_);
  const float sc   = inv * gamma[gid];
  scale[gid] = sc;
  shift[gid] = fmaf(-mean, sc, beta[gid]);
}

// ---------------- Kernel 3: normalize ------------------------------------
__global__ __launch_bounds__(256) void k_norm(
    const float4* __restrict__ X4, const int* __restrict__ dd,
    const float4* __restrict__ scale4, const float4* __restrict__ shift4,
    float4* __restrict__ Y4, int total4) {
  int i = blockIdx.x * 256 + threadIdx.x;
  const int stride = gridDim.x * 256;
  for (; i < total4; i += stride) {
    const int n  = i >> 7;          // C/4 = 128 float4 per row
    const int c4 = i & 127;
    const int dn = dd[n];           // wave-uniform (128 float4 per row)
    const float4 x  = X4[i];
    const float4 sc = scale4[dn * (C_ / 4) + c4];
    const float4 sh = shift4[dn * (C_ / 4) + c4];
    float4 y;
    y.x = fmaf(x.x, sc.x, sh.x);
    y.y = fmaf(x.y, sc.y, sh.y);
    y.z = fmaf(x.z, sc.z, sh.z);
    y.w = fmaf(x.w, sc.w, sh.w);
    Y4[i] = y;
  }
}

extern "C" void kernel_launch(void* const* d_in, const int* in_sizes, int n_in,
                              void* d_out, int out_size, void* d_ws, size_t ws_size,
                              hipStream_t stream) {
  const float* X     = (const float*)d_in[0];
  const int*   dd    = (const int*)  d_in[1];
  // d_in[2] = parameter_t, d_in[3] = fm_mean : unused by the reference math
  const float* gamma = (const float*)d_in[4];
  const float* beta  = (const float*)d_in[5];
  float*       out   = (float*)d_out;

  const int N      = in_sizes[1];             // 65536
  const int rpc    = 256;                     // rows per chunk
  const int NCHUNK = (N + rpc - 1) / rpc;     // 256

  // Atomic accumulators live in the TAIL of d_out (512 KB + cnt). They are
  // consumed by k_finalize before k_norm overwrites the region (stream order).
  const size_t accN = (size_t)NREP * ND_ * C_;          // 65536 floats each
  float* acc_sum = out + (size_t)out_size - (2 * accN + 16);
  float* acc_sq  = acc_sum + accN;
  int*   cnt     = (int*)(acc_sq + accN);
  hipMemsetAsync(acc_sum, 0, (2 * accN + 16) * sizeof(float), stream);

  // scale/shift must survive into k_norm -> d_ws (64 KB).
  float* scale = (float*)d_ws;
  float* shift = scale + ND_ * C_;

  dim3 g1(2, NCHUNK);
  k_stats<<<g1, 256, 0, stream>>>((const float2*)X, dd, acc_sum, acc_sq,
                                  cnt, rpc, N);
  k_finalize<<<(ND_ * C_) / 128, 128, 0, stream>>>(
      acc_sum, acc_sq, cnt, gamma, beta, scale, shift);

  const int total4 = N * (C_ / 4);
  int blocks = (total4 + 255) / 256;
  if (blocks > 2048) blocks = 2048;
  k_norm<<<blocks, 256, 0, stream>>>((const float4*)X, dd,
                                     (const float4*)scale,
                                     (const float4*)shift,
                                     (float4*)out, total4);
}